// Round 4
// baseline (465.171 us; speedup 1.0000x reference)
//
#include <hip/hip_runtime.h>
#include <hip/hip_bf16.h>
#include <cstdint>

#define N_NODES 20000
#define N_EDGES 640000
#define NPAD    20096   // 157 * 128, padded row count for MFMA tiles

typedef __bf16 bf16_8 __attribute__((ext_vector_type(8)));
typedef float  f32_4  __attribute__((ext_vector_type(4)));

// ---------------------------------------------------------------------------
// CSR build: count -> scan (wave-shuffle based) -> fill
// ---------------------------------------------------------------------------

__global__ void count_deg_kernel(const int* __restrict__ dst, int* __restrict__ deg) {
    int e = blockIdx.x * blockDim.x + threadIdx.x;
    if (e < N_EDGES) atomicAdd(&deg[dst[e]], 1);
}

__global__ __launch_bounds__(1024) void scan_deg_kernel(const int* __restrict__ deg,
                                                        int* __restrict__ row_start,
                                                        int* __restrict__ cursor,
                                                        float* __restrict__ dinv) {
    __shared__ int wsum[16];
    __shared__ int chunk_base;
    const int t = threadIdx.x, lane = t & 63, w = t >> 6;
    if (t == 0) chunk_base = 0;
    __syncthreads();
    for (int base = 0; base < N_NODES; base += 1024) {
        int i = base + t;
        int v = (i < N_NODES) ? deg[i] : 0;
        if (i < N_NODES) dinv[i] = rsqrtf((float)(v + 1));
        // wave inclusive scan
        int incl = v;
        #pragma unroll
        for (int off = 1; off < 64; off <<= 1) {
            int u = __shfl_up(incl, off);
            if (lane >= off) incl += u;
        }
        if (lane == 63) wsum[w] = incl;
        __syncthreads();
        if (w == 0) {
            int s = (lane < 16) ? wsum[lane] : 0;
            #pragma unroll
            for (int off = 1; off < 16; off <<= 1) {
                int u = __shfl_up(s, off);
                if (lane >= off) s += u;
            }
            if (lane < 16) wsum[lane] = s;   // inclusive over wave sums
        }
        __syncthreads();
        int wbase = (w == 0) ? 0 : wsum[w - 1];
        int excl  = chunk_base + wbase + incl - v;
        if (i < N_NODES) { row_start[i] = excl; cursor[i] = excl; }
        int total = wsum[15];
        __syncthreads();
        if (t == 0) chunk_base += total;
        __syncthreads();
    }
    if (t == 0) row_start[N_NODES] = chunk_base;
}

__global__ void fill_col_kernel(const int* __restrict__ src, const int* __restrict__ dst,
                                int* __restrict__ cursor, int* __restrict__ col) {
    int e = blockIdx.x * blockDim.x + threadIdx.x;
    if (e < N_EDGES) {
        int d = dst[e];
        int pos = atomicAdd(&cursor[d], 1);
        col[pos] = src[e];
    }
}

// ---------------------------------------------------------------------------
// Chunked aggregation: grid.y = 32-channel chunk (slab 2.56 MB fits XCD L2).
// One wave per (node, chunk); lanes 0-31 even edges, 32-63 odd edges.
// ---------------------------------------------------------------------------

template<int M, bool BIAS>
__global__ __launch_bounds__(256) void agg_kernel(const float* __restrict__ x,
                                                  const int* __restrict__ row_start,
                                                  const int* __restrict__ col,
                                                  const float* __restrict__ dinv,
                                                  const float* __restrict__ bias,
                                                  float* __restrict__ out) {
    const int lane = threadIdx.x & 63;
    const int wid  = threadIdx.x >> 6;
    const int n    = blockIdx.x * 4 + wid;
    if (n >= N_NODES) return;                 // wave-uniform; no barriers below
    const int c    = blockIdx.y * 32 + (lane & 31);
    const int half = lane >> 5;
    const float dn = dinv[n];
    const int s0 = row_start[n];
    const int s1 = row_start[n + 1];

    float a0 = 0.f, a1 = 0.f, a2 = 0.f, a3 = 0.f;
    if (!half) a0 = dn * x[(size_t)n * M + c];    // self-loop term

    int e = s0 + half;
    while (e + 6 < s1) {
        int sa = col[e], sb = col[e + 2], sc = col[e + 4], sd = col[e + 6];
        a0 += dinv[sa] * x[(size_t)sa * M + c];
        a1 += dinv[sb] * x[(size_t)sb * M + c];
        a2 += dinv[sc] * x[(size_t)sc * M + c];
        a3 += dinv[sd] * x[(size_t)sd * M + c];
        e += 8;
    }
    while (e < s1) {
        int sa = col[e];
        a0 += dinv[sa] * x[(size_t)sa * M + c];
        e += 2;
    }
    float acc = (a0 + a2) + (a1 + a3);
    acc += __shfl_xor(acc, 32);
    if (lane < 32) {
        float r = dn * acc;
        if (BIAS) r += bias[c];
        out[(size_t)n * M + c] = r;
    }
}

// ---------------------------------------------------------------------------
// Conversion: fp32 X[N][K] -> Ae bf16 [NPAD][2K]  ([0:K]=hi, [K:2K]=lo)
// Rows >= N_NODES zero-filled.
// ---------------------------------------------------------------------------

template<int K>
__global__ __launch_bounds__(256) void convA_kernel(const float* __restrict__ X,
                                                    unsigned short* __restrict__ Ae) {
    const int tid = blockIdx.x * blockDim.x + threadIdx.x;
    const int quads_per_row = K / 4;
    if (tid >= NPAD * quads_per_row) return;
    const int n = tid / quads_per_row;
    const int q = (tid - n * quads_per_row) * 4;
    float4 v = make_float4(0.f, 0.f, 0.f, 0.f);
    if (n < N_NODES) v = *reinterpret_cast<const float4*>(X + (size_t)n * K + q);
    ushort4 hi, lo;
    float f;
    __hip_bfloat16 h;
    h = __float2bfloat16(v.x); f = __bfloat162float(h); hi.x = __hip_bfloat16_raw(h).x; lo.x = __hip_bfloat16_raw(__float2bfloat16(v.x - f)).x;
    h = __float2bfloat16(v.y); f = __bfloat162float(h); hi.y = __hip_bfloat16_raw(h).x; lo.y = __hip_bfloat16_raw(__float2bfloat16(v.y - f)).x;
    h = __float2bfloat16(v.z); f = __bfloat162float(h); hi.z = __hip_bfloat16_raw(h).x; lo.z = __hip_bfloat16_raw(__float2bfloat16(v.z - f)).x;
    h = __float2bfloat16(v.w); f = __bfloat162float(h); hi.w = __hip_bfloat16_raw(h).x; lo.w = __hip_bfloat16_raw(__float2bfloat16(v.w - f)).x;
    *reinterpret_cast<ushort4*>(Ae + (size_t)n * (2 * K) + q)     = hi;
    *reinterpret_cast<ushort4*>(Ae + (size_t)n * (2 * K) + K + q) = lo;
}

// W[K][M] fp32 -> BT [M][2K] bf16  ([m][0:K]=hi(W[:,m]), [m][K:2K]=lo)
template<int K, int M>
__global__ __launch_bounds__(256) void convW_kernel(const float* __restrict__ W,
                                                    unsigned short* __restrict__ BT) {
    const int tid = blockIdx.x * blockDim.x + threadIdx.x;
    if (tid >= K * M) return;
    const int k = tid / M;
    const int m = tid - k * M;
    float x = W[(size_t)k * M + m];
    __hip_bfloat16 h = __float2bfloat16(x);
    float hf = __bfloat162float(h);
    __hip_bfloat16 l = __float2bfloat16(x - hf);
    BT[(size_t)m * (2 * K) + k]     = __hip_bfloat16_raw(h).x;
    BT[(size_t)m * (2 * K) + K + k] = __hip_bfloat16_raw(l).x;
}

// ---------------------------------------------------------------------------
// MFMA GEMM: C[N][M] = sum over 3 segments { Ahi*Bhi, Ahi*Blo, Alo*Bhi }
// Tile 128x64, 4 waves (2x2), BK=32, 16x16x32 bf16 MFMA, global_load_lds.
// ---------------------------------------------------------------------------

template<int K, int M, bool RELUBIAS>
__global__ __launch_bounds__(256) void mfma_gemm_kernel(const unsigned short* __restrict__ Ae, // [NPAD][2K]
                                                        const unsigned short* __restrict__ BT, // [M][2K]
                                                        const float* __restrict__ bias,
                                                        float* __restrict__ C) {
    constexpr int K2 = 2 * K;
    __shared__ unsigned short As[128 * 32];   // [row][k] 64B row stride
    __shared__ unsigned short Bs[64 * 32];    // [col][k]
    const int tid  = threadIdx.x;
    const int lane = tid & 63;
    const int wid  = tid >> 6;
    const int brow = blockIdx.x * 128;
    const int bcol = blockIdx.y * 64;
    const int wr = wid & 1, wc = wid >> 1;

    const int arow0 = wid * 32 + (lane >> 2);   // first staged A row for this thread
    const int bcolr = wid * 16 + (lane >> 2);   // staged B col
    const int ke8   = (lane & 3) * 8;           // k element offset within 32

    f32_4 acc[4][2];
    #pragma unroll
    for (int r = 0; r < 4; ++r)
        #pragma unroll
        for (int c = 0; c < 2; ++c) acc[r][c] = (f32_4){0.f, 0.f, 0.f, 0.f};

    for (int ks = 0; ks < 3 * K / 32; ++ks) {
        const int k0  = ks * 32;
        const int seg = k0 / K;
        const int kk  = k0 - seg * K;
        const int aoff = (seg == 2) ? K + kk : kk;   // hi, hi, lo
        const int boff = (seg == 1) ? K + kk : kk;   // hi, lo, hi

        const unsigned short* g0 = Ae + (size_t)(brow + arow0) * K2 + aoff + ke8;
        const unsigned short* g1 = g0 + (size_t)16 * K2;
        const unsigned short* gb = BT + (size_t)(bcol + bcolr) * K2 + boff + ke8;
        char* l0 = (char*)As + wid * 2048;
        char* l1 = l0 + 1024;
        char* lb = (char*)Bs + wid * 1024;
        __builtin_amdgcn_global_load_lds((const __attribute__((address_space(1))) void*)g0,
                                         (__attribute__((address_space(3))) void*)l0, 16, 0, 0);
        __builtin_amdgcn_global_load_lds((const __attribute__((address_space(1))) void*)g1,
                                         (__attribute__((address_space(3))) void*)l1, 16, 0, 0);
        __builtin_amdgcn_global_load_lds((const __attribute__((address_space(1))) void*)gb,
                                         (__attribute__((address_space(3))) void*)lb, 16, 0, 0);
        __syncthreads();

        bf16_8 a[4], b[2];
        #pragma unroll
        for (int r = 0; r < 4; ++r) {
            int off = (wr * 64 + r * 16 + (lane & 15)) * 32 + (lane >> 4) * 8;
            a[r] = *reinterpret_cast<const bf16_8*>(&As[off]);
        }
        #pragma unroll
        for (int c = 0; c < 2; ++c) {
            int off = (wc * 32 + c * 16 + (lane & 15)) * 32 + (lane >> 4) * 8;
            b[c] = *reinterpret_cast<const bf16_8*>(&Bs[off]);
        }
        #pragma unroll
        for (int r = 0; r < 4; ++r)
            #pragma unroll
            for (int c = 0; c < 2; ++c)
                acc[r][c] = __builtin_amdgcn_mfma_f32_16x16x32_bf16(a[r], b[c], acc[r][c], 0, 0, 0);
        __syncthreads();
    }

    // Epilogue: C/D layout col=lane&15, row=(lane>>4)*4+q  [m89-verified]
    #pragma unroll
    for (int c = 0; c < 2; ++c) {
        const int n  = bcol + wc * 32 + c * 16 + (lane & 15);
        const float bv = RELUBIAS ? bias[n] : 0.f;
        #pragma unroll
        for (int r = 0; r < 4; ++r) {
            const int row0 = brow + wr * 64 + r * 16 + (lane >> 4) * 4;
            #pragma unroll
            for (int q = 0; q < 4; ++q) {
                const int row = row0 + q;
                if (row < N_NODES) {
                    float v = acc[r][c][q];
                    if (RELUBIAS) v = fmaxf(v + bv, 0.f);
                    C[(size_t)row * M + n] = v;
                }
            }
        }
    }
}

// ---------------------------------------------------------------------------
// Launch
// ---------------------------------------------------------------------------

static inline char* align_up(char* p, size_t a) {
    return (char*)(((uintptr_t)p + a - 1) & ~(a - 1));
}

extern "C" void kernel_launch(void* const* d_in, const int* in_sizes, int n_in,
                              void* d_out, int out_size, void* d_ws, size_t ws_size,
                              hipStream_t stream) {
    const int*   edge_index = (const int*)d_in[0];
    const float* node_emb   = (const float*)d_in[1];
    const float* W1 = (const float*)d_in[2];
    const float* b1 = (const float*)d_in[3];
    const float* W2 = (const float*)d_in[4];
    const float* b2 = (const float*)d_in[5];
    const float* W3 = (const float*)d_in[6];
    const float* b3 = (const float*)d_in[7];
    float* out = (float*)d_out;

    const int* src = edge_index;
    const int* dst = edge_index + N_EDGES;

    // Workspace carve-up (~44.6 MB)
    char* p = (char*)d_ws;
    int* deg       = (int*)p;            p = align_up(p + N_NODES * sizeof(int), 256);
    int* row_start = (int*)p;            p = align_up(p + (N_NODES + 1) * sizeof(int), 256);
    int* cursor    = (int*)p;            p = align_up(p + N_NODES * sizeof(int), 256);
    int* col       = (int*)p;            p = align_up(p + N_EDGES * sizeof(int), 256);
    float* dinv    = (float*)p;          p = align_up(p + N_NODES * sizeof(float), 256);
    unsigned short* BT = (unsigned short*)p; p = align_up(p + 256 * 512 * sizeof(unsigned short), 256);
    // two ping-pong buffers, each big enough for [N,256] f32 or [NPAD,512] bf16
    const size_t BUF_BYTES = (size_t)NPAD * 512 * 2;   // 20.58 MB
    char* buf0 = p;                      p = align_up(p + BUF_BYTES, 256);
    char* buf1 = p;                      p = align_up(p + BUF_BYTES, 256);

    float*          X  = (float*)buf0;
    float*          Y  = (float*)buf1;
    unsigned short* Xs = (unsigned short*)buf0;
    unsigned short* Ys = (unsigned short*)buf1;

    // --- CSR build (shared across all 3 layers) ---
    hipMemsetAsync(deg, 0, N_NODES * sizeof(int), stream);
    count_deg_kernel<<<(N_EDGES + 255) / 256, 256, 0, stream>>>(dst, deg);
    scan_deg_kernel<<<1, 1024, 0, stream>>>(deg, row_start, cursor, dinv);
    fill_col_kernel<<<(N_EDGES + 255) / 256, 256, 0, stream>>>(src, dst, cursor, col);

    const int NG = (N_NODES + 3) / 4;   // 5000 node-groups (4 nodes/block)

    // --- Layer 1: g1 = Agg(emb) [N,128] -> X ; h1 = relu(g1@W1+b1) [N,256] -> X
    agg_kernel<128, false><<<dim3(NG, 4), 256, 0, stream>>>(node_emb, row_start, col, dinv, nullptr, X);
    convA_kernel<128><<<(NPAD * 32 + 255) / 256, 256, 0, stream>>>(X, Ys);
    convW_kernel<128, 256><<<(128 * 256 + 255) / 256, 256, 0, stream>>>(W1, BT);
    mfma_gemm_kernel<128, 256, true><<<dim3(NPAD / 128, 4), 256, 0, stream>>>(Ys, BT, b1, X);

    // --- Layer 2: g2 = Agg(h1) [N,256] -> Y ; h2 = relu(g2@W2+b2) [N,256] -> Y
    agg_kernel<256, false><<<dim3(NG, 8), 256, 0, stream>>>(X, row_start, col, dinv, nullptr, Y);
    convA_kernel<256><<<(NPAD * 64 + 255) / 256, 256, 0, stream>>>(Y, Xs);
    convW_kernel<256, 256><<<(256 * 256 + 255) / 256, 256, 0, stream>>>(W2, BT);
    mfma_gemm_kernel<256, 256, true><<<dim3(NPAD / 128, 4), 256, 0, stream>>>(Xs, BT, b2, Y);

    // --- Layer 3: g3 = h2@W3 [N,128] -> Y' ; out = Agg(g3) + b3
    convA_kernel<256><<<(NPAD * 64 + 255) / 256, 256, 0, stream>>>(Y, Xs);
    convW_kernel<256, 128><<<(256 * 128 + 255) / 256, 256, 0, stream>>>(W3, BT);
    mfma_gemm_kernel<256, 128, false><<<dim3(NPAD / 128, 2), 256, 0, stream>>>(Xs, BT, nullptr, Y);
    agg_kernel<128, true><<<dim3(NG, 4), 256, 0, stream>>>(Y, row_start, col, dinv, b3, out);
}

// Round 10
// 432.711 us; speedup vs baseline: 1.0750x; 1.0750x over previous
//
#include <hip/hip_runtime.h>
#include <hip/hip_bf16.h>
#include <cstdint>

#define N_NODES 20000
#define N_EDGES 640000
#define NPAD    20096   // 157 * 128

typedef __bf16 bf16_8 __attribute__((ext_vector_type(8)));
typedef float  f32_4  __attribute__((ext_vector_type(4)));
typedef unsigned short u16x4 __attribute__((ext_vector_type(4)));

// ---------------------------------------------------------------------------
// CSR build: count -> scan -> fill  (graph shared by all 3 layers)
// ---------------------------------------------------------------------------

__global__ void count_deg_kernel(const int* __restrict__ dst, int* __restrict__ deg) {
    int e = blockIdx.x * blockDim.x + threadIdx.x;
    if (e < N_EDGES) atomicAdd(&deg[dst[e]], 1);
}

__global__ __launch_bounds__(1024) void scan_deg_kernel(const int* __restrict__ deg,
                                                        int* __restrict__ row_start,
                                                        int* __restrict__ cursor,
                                                        float* __restrict__ dinv) {
    __shared__ int wsum[16];
    __shared__ int chunk_base;
    const int t = threadIdx.x, lane = t & 63, w = t >> 6;
    if (t == 0) chunk_base = 0;
    __syncthreads();
    for (int base = 0; base < N_NODES; base += 1024) {
        int i = base + t;
        int v = (i < N_NODES) ? deg[i] : 0;
        if (i < N_NODES) dinv[i] = rsqrtf((float)(v + 1));
        int incl = v;
        #pragma unroll
        for (int off = 1; off < 64; off <<= 1) {
            int u = __shfl_up(incl, off);
            if (lane >= off) incl += u;
        }
        if (lane == 63) wsum[w] = incl;
        __syncthreads();
        if (w == 0) {
            int s = (lane < 16) ? wsum[lane] : 0;
            #pragma unroll
            for (int off = 1; off < 16; off <<= 1) {
                int u = __shfl_up(s, off);
                if (lane >= off) s += u;
            }
            if (lane < 16) wsum[lane] = s;
        }
        __syncthreads();
        int wbase = (w == 0) ? 0 : wsum[w - 1];
        int excl  = chunk_base + wbase + incl - v;
        if (i < N_NODES) { row_start[i] = excl; cursor[i] = excl; }
        int total = wsum[15];
        __syncthreads();
        if (t == 0) chunk_base += total;
        __syncthreads();
    }
    if (t == 0) row_start[N_NODES] = chunk_base;
}

__global__ void fill_col_kernel(const int* __restrict__ src, const int* __restrict__ dst,
                                int* __restrict__ cursor, int* __restrict__ col) {
    int e = blockIdx.x * blockDim.x + threadIdx.x;
    if (e < N_EDGES) {
        int d = dst[e];
        int pos = atomicAdd(&cursor[d], 1);
        col[pos] = src[e];
    }
}

// xs0 = dinv (.) emb   [N,128] f32
__global__ __launch_bounds__(256) void scale_emb_kernel(const float* __restrict__ emb,
                                                        const float* __restrict__ dinv,
                                                        float* __restrict__ xs) {
    int tid = blockIdx.x * 256 + threadIdx.x;       // one float4 per thread
    if (tid >= N_NODES * 32) return;
    int n = tid >> 5;
    int q = (tid & 31) * 4;
    f32_4 v = *reinterpret_cast<const f32_4*>(emb + (size_t)n * 128 + q);
    float d = dinv[n];
    v.x *= d; v.y *= d; v.z *= d; v.w *= d;
    *reinterpret_cast<f32_4*>(xs + (size_t)n * 128 + q) = v;
}

// ---------------------------------------------------------------------------
// Aggregation (input pre-scaled by dinv): out[n] = dinv[n]*(sum xs[s] + xs[n])
// Wave = (node, 32-ch chunk). lane -> (edge slot = lane>>3, ch quad = (lane&7)*4)
// 8 edges in flight per instruction, x2 unroll; butterfly reduce over slots.
// SPLIT: write bf16 hi/lo pair [n][2M] for the MFMA GEMM A-input.
// ---------------------------------------------------------------------------

__device__ inline ushort2 bf_split(float v) {
    __hip_bfloat16 h = __float2bfloat16(v);
    float hf = __bfloat162float(h);
    unsigned short lo = __hip_bfloat16_raw(__float2bfloat16(v - hf)).x;
    ushort2 r; r.x = __hip_bfloat16_raw(h).x; r.y = lo; return r;
}

template<int M, bool SPLIT, bool BIAS>
__global__ __launch_bounds__(256) void agg_kernel(const float* __restrict__ xs,
                                                  const int* __restrict__ rs,
                                                  const int* __restrict__ col,
                                                  const float* __restrict__ dinv,
                                                  const float* __restrict__ bias,
                                                  float* __restrict__ outf,
                                                  unsigned short* __restrict__ outb) {
    const int lane = threadIdx.x & 63;
    const int wid  = threadIdx.x >> 6;
    const int n    = blockIdx.x * 4 + wid;          // grid.x = 5000 -> n < 20000
    const int cb   = blockIdx.y * 32;
    const int c4   = (lane & 7) * 4;
    const int es   = lane >> 3;                     // edge slot 0..7
    const float dn = dinv[n];
    const int s0 = rs[n], s1 = rs[n + 1];
    const float* __restrict__ xb = xs + cb + c4;

    f32_4 acc = {0.f, 0.f, 0.f, 0.f};
    if (es == 0) acc = *reinterpret_cast<const f32_4*>(xb + (size_t)n * M);  // self

    int i = s0 + es;
    for (; i + 8 < s1; i += 16) {
        int sa = __builtin_nontemporal_load(col + i);
        int sb = __builtin_nontemporal_load(col + i + 8);
        f32_4 va = *reinterpret_cast<const f32_4*>(xb + (size_t)sa * M);
        f32_4 vb = *reinterpret_cast<const f32_4*>(xb + (size_t)sb * M);
        acc += va;
        acc += vb;
    }
    if (i < s1) {
        int sa = __builtin_nontemporal_load(col + i);
        acc += *reinterpret_cast<const f32_4*>(xb + (size_t)sa * M);
    }

    // reduce across the 8 edge slots
    #pragma unroll
    for (int m = 8; m < 64; m <<= 1) {
        acc.x += __shfl_xor(acc.x, m);
        acc.y += __shfl_xor(acc.y, m);
        acc.z += __shfl_xor(acc.z, m);
        acc.w += __shfl_xor(acc.w, m);
    }

    if (lane < 8) {
        f32_4 r;
        r.x = dn * acc.x; r.y = dn * acc.y; r.z = dn * acc.z; r.w = dn * acc.w;
        if (BIAS) {
            r.x += bias[cb + c4 + 0]; r.y += bias[cb + c4 + 1];
            r.z += bias[cb + c4 + 2]; r.w += bias[cb + c4 + 3];
        }
        if (SPLIT) {
            ushort2 sx = bf_split(r.x), sy = bf_split(r.y), sz = bf_split(r.z), sw = bf_split(r.w);
            u16x4 hi = {sx.x, sy.x, sz.x, sw.x};
            u16x4 lo = {sx.y, sy.y, sz.y, sw.y};
            unsigned short* pb = outb + (size_t)n * (2 * M) + cb + c4;
            __builtin_nontemporal_store(hi, reinterpret_cast<u16x4*>(pb));
            __builtin_nontemporal_store(lo, reinterpret_cast<u16x4*>(pb + M));
        } else {
            __builtin_nontemporal_store(r, reinterpret_cast<f32_4*>(outf + (size_t)n * M + cb + c4));
        }
    }
}

// ---------------------------------------------------------------------------
// fp32 X[N][256] -> bf16 hi/lo [NPAD][512], pad rows zero-filled
// ---------------------------------------------------------------------------

__global__ __launch_bounds__(256) void convA256_kernel(const float* __restrict__ X,
                                                       unsigned short* __restrict__ Ae) {
    const int tid = blockIdx.x * blockDim.x + threadIdx.x;
    if (tid >= NPAD * 64) return;
    const int n = tid >> 6;
    const int q = (tid & 63) * 4;
    f32_4 v = {0.f, 0.f, 0.f, 0.f};
    if (n < N_NODES) v = *reinterpret_cast<const f32_4*>(X + (size_t)n * 256 + q);
    ushort2 sx = bf_split(v.x), sy = bf_split(v.y), sz = bf_split(v.z), sw = bf_split(v.w);
    u16x4 hi = {sx.x, sy.x, sz.x, sw.x};
    u16x4 lo = {sx.y, sy.y, sz.y, sw.y};
    *reinterpret_cast<u16x4*>(Ae + (size_t)n * 512 + q)       = hi;
    *reinterpret_cast<u16x4*>(Ae + (size_t)n * 512 + 256 + q) = lo;
}

// W[K][M] fp32 -> BT [M][2K] bf16
template<int K, int M>
__global__ __launch_bounds__(256) void convW_kernel(const float* __restrict__ W,
                                                    unsigned short* __restrict__ BT) {
    const int tid = blockIdx.x * blockDim.x + threadIdx.x;
    if (tid >= K * M) return;
    const int k = tid / M;
    const int m = tid - k * M;
    ushort2 s = bf_split(W[(size_t)k * M + m]);
    BT[(size_t)m * (2 * K) + k]     = s.x;
    BT[(size_t)m * (2 * K) + K + k] = s.y;
}

// ---------------------------------------------------------------------------
// MFMA GEMM, 3-segment bf16 hi/lo split: C = Ahi*Bhi + Ahi*Blo + Alo*Bhi
// Tile 128 x BN (BN=64|128), 4 waves (2x2), BK=32, 16x16x32 bf16.
// Epilogue: optional relu(v+bias), optional *dinv[row] (pre-scale for next agg).
// ---------------------------------------------------------------------------

template<int K, int BN, bool RELU, bool SCALE>
__global__ __launch_bounds__(256) void mfma_gemm_kernel(const unsigned short* __restrict__ Ae, // [NPAD][2K]
                                                        const unsigned short* __restrict__ BT, // [M][2K]
                                                        const float* __restrict__ bias,
                                                        const float* __restrict__ dinv,
                                                        float* __restrict__ C, int Mout) {
    constexpr int K2 = 2 * K;
    constexpr int CF = BN / 32;          // b-fragments per wave (2 or 4)
    __shared__ unsigned short As[128 * 32];
    __shared__ unsigned short Bs[BN * 32];
    const int tid  = threadIdx.x;
    const int lane = tid & 63;
    const int wid  = tid >> 6;
    const int brow = blockIdx.x * 128;
    const int bcol = blockIdx.y * BN;
    const int wr = wid & 1, wc = wid >> 1;

    const int arow0 = wid * 32 + (lane >> 2);        // staged A row
    const int bcol0 = wid * (BN / 4) + (lane >> 2);  // staged B col
    const int ke8   = (lane & 3) * 8;

    f32_4 acc[4][CF];
    #pragma unroll
    for (int r = 0; r < 4; ++r)
        #pragma unroll
        for (int c = 0; c < CF; ++c) acc[r][c] = (f32_4){0.f, 0.f, 0.f, 0.f};

    for (int ks = 0; ks < 3 * K / 32; ++ks) {
        const int k0  = ks * 32;
        const int seg = k0 / K;
        const int kk  = k0 - seg * K;
        const int aoff = (seg == 2) ? K + kk : kk;   // A: hi, hi, lo
        const int boff = (seg == 1) ? K + kk : kk;   // B: hi, lo, hi

        const unsigned short* g0 = Ae + (size_t)(brow + arow0) * K2 + aoff + ke8;
        const unsigned short* g1 = g0 + (size_t)16 * K2;
        char* l0 = (char*)As + wid * 2048;
        __builtin_amdgcn_global_load_lds((const __attribute__((address_space(1))) void*)g0,
                                         (__attribute__((address_space(3))) void*)l0, 16, 0, 0);
        __builtin_amdgcn_global_load_lds((const __attribute__((address_space(1))) void*)g1,
                                         (__attribute__((address_space(3))) void*)(l0 + 1024), 16, 0, 0);
        const unsigned short* gb = BT + (size_t)(bcol + bcol0) * K2 + boff + ke8;
        char* lb = (char*)Bs + wid * (BN * 16);      // 16 (BN=64) or 32 (BN=128) cols/wave, 64 B/col
        __builtin_amdgcn_global_load_lds((const __attribute__((address_space(1))) void*)gb,
                                         (__attribute__((address_space(3))) void*)lb, 16, 0, 0);
        if constexpr (BN == 128) {
            const unsigned short* gb2 = gb + (size_t)16 * K2;
            __builtin_amdgcn_global_load_lds((const __attribute__((address_space(1))) void*)gb2,
                                             (__attribute__((address_space(3))) void*)(lb + 1024), 16, 0, 0);
        }
        __syncthreads();

        bf16_8 a[4], b[CF];
        #pragma unroll
        for (int r = 0; r < 4; ++r) {
            int off = (wr * 64 + r * 16 + (lane & 15)) * 32 + (lane >> 4) * 8;
            a[r] = *reinterpret_cast<const bf16_8*>(&As[off]);
        }
        #pragma unroll
        for (int c = 0; c < CF; ++c) {
            int off = (wc * (BN / 2) + c * 16 + (lane & 15)) * 32 + (lane >> 4) * 8;
            b[c] = *reinterpret_cast<const bf16_8*>(&Bs[off]);
        }
        #pragma unroll
        for (int r = 0; r < 4; ++r)
            #pragma unroll
            for (int c = 0; c < CF; ++c)
                acc[r][c] = __builtin_amdgcn_mfma_f32_16x16x32_bf16(a[r], b[c], acc[r][c], 0, 0, 0);
        __syncthreads();
    }

    // Epilogue: C/D layout col=lane&15, row=(lane>>4)*4+q
    #pragma unroll
    for (int r = 0; r < 4; ++r) {
        const int row0 = brow + wr * 64 + r * 16 + (lane >> 4) * 4;
        f32_4 dv = {1.f, 1.f, 1.f, 1.f};
        if (SCALE) dv = *reinterpret_cast<const f32_4*>(dinv + row0);   // quad-aligned
        #pragma unroll
        for (int c = 0; c < CF; ++c) {
            const int n  = bcol + wc * (BN / 2) + c * 16 + (lane & 15);
            const float bv = RELU ? bias[n] : 0.f;
            #pragma unroll
            for (int q = 0; q < 4; ++q) {
                const int row = row0 + q;
                if (row < N_NODES) {
                    float v = acc[r][c][q];
                    if (RELU)  v = fmaxf(v + bv, 0.f);
                    if (SCALE) v *= dv[q];
                    C[(size_t)row * Mout + n] = v;
                }
            }
        }
    }
}

// ---------------------------------------------------------------------------
// Launch
// ---------------------------------------------------------------------------

static inline char* align_up(char* p, size_t a) {
    return (char*)(((uintptr_t)p + a - 1) & ~(a - 1));
}

extern "C" void kernel_launch(void* const* d_in, const int* in_sizes, int n_in,
                              void* d_out, int out_size, void* d_ws, size_t ws_size,
                              hipStream_t stream) {
    const int*   edge_index = (const int*)d_in[0];
    const float* node_emb   = (const float*)d_in[1];
    const float* W1 = (const float*)d_in[2];
    const float* b1 = (const float*)d_in[3];
    const float* W2 = (const float*)d_in[4];
    const float* b2 = (const float*)d_in[5];
    const float* W3 = (const float*)d_in[6];
    const float* b3 = (const float*)d_in[7];
    float* out = (float*)d_out;

    const int* src = edge_index;
    const int* dst = edge_index + N_EDGES;

    // Workspace carve-up (~45 MB)
    char* p = (char*)d_ws;
    int* deg       = (int*)p;            p = align_up(p + N_NODES * sizeof(int), 256);
    int* rs        = (int*)p;            p = align_up(p + (N_NODES + 1) * sizeof(int), 256);
    int* cursor    = (int*)p;            p = align_up(p + N_NODES * sizeof(int), 256);
    int* col       = (int*)p;            p = align_up(p + N_EDGES * sizeof(int), 256);
    float* dinv    = (float*)p;          p = align_up(p + N_NODES * sizeof(float), 512);
    unsigned short* BT = (unsigned short*)p; p = align_up(p + 256 * 512 * sizeof(unsigned short), 256);
    const size_t SLOT = (size_t)NPAD * 512 * 2;   // 20.58 MB, fits [N,256]f32 or [NPAD][512]bf16
    char* slotA = p;                     p = align_up(p + SLOT, 256);
    char* slotB = p;                     p = align_up(p + SLOT, 256);

    float*          fA = (float*)slotA;
    unsigned short* uB = (unsigned short*)slotB;

    // --- CSR + dinv ---
    hipMemsetAsync(deg, 0, N_NODES * sizeof(int), stream);
    count_deg_kernel<<<(N_EDGES + 255) / 256, 256, 0, stream>>>(dst, deg);
    scan_deg_kernel<<<1, 1024, 0, stream>>>(deg, rs, cursor, dinv);
    fill_col_kernel<<<(N_EDGES + 255) / 256, 256, 0, stream>>>(src, dst, cursor, col);

    // xs0 = dinv (.) emb  -> slotA
    scale_emb_kernel<<<(N_NODES * 32 + 255) / 256, 256, 0, stream>>>(node_emb, dinv, fA);

    // --- Layer 1: agg1 -> Ae1(bf16, slotB); G1 = relu(.@W1+b1)*dinv -> X(f32, slotA)
    agg_kernel<128, true, false><<<dim3(5000, 4), 256, 0, stream>>>(fA, rs, col, dinv, nullptr, nullptr, uB);
    convW_kernel<128, 256><<<(128 * 256) / 256, 256, 0, stream>>>(W1, BT);
    mfma_gemm_kernel<128, 128, true, true><<<dim3(NPAD / 128, 2), 256, 0, stream>>>(uB, BT, b1, dinv, fA, 256);

    // --- Layer 2: agg2 -> Ae2(bf16, slotB); G2 = relu(.@W2+b2) -> H(f32, slotA)
    agg_kernel<256, true, false><<<dim3(5000, 8), 256, 0, stream>>>(fA, rs, col, dinv, nullptr, nullptr, uB);
    convW_kernel<256, 256><<<(256 * 256) / 256, 256, 0, stream>>>(W2, BT);
    mfma_gemm_kernel<256, 128, true, false><<<dim3(NPAD / 128, 2), 256, 0, stream>>>(uB, BT, b2, dinv, fA, 256);

    // --- Layer 3: conv H -> He(bf16, slotB); G3 = (.@W3)*dinv -> G(f32, slotA); agg3 -> out
    convA256_kernel<<<(NPAD * 64 + 255) / 256, 256, 0, stream>>>(fA, uB);
    convW_kernel<256, 128><<<(256 * 128) / 256, 256, 0, stream>>>(W3, BT);
    mfma_gemm_kernel<256, 64, false, true><<<dim3(NPAD / 128, 2), 256, 0, stream>>>(uB, BT, nullptr, dinv, fA, 128);
    agg_kernel<128, false, true><<<dim3(5000, 4), 256, 0, stream>>>(fA, rs, col, dinv, b3, out, nullptr);
}

// Round 11
// 406.687 us; speedup vs baseline: 1.1438x; 1.0640x over previous
//
#include <hip/hip_runtime.h>
#include <hip/hip_bf16.h>
#include <cstdint>

#define N_NODES 20000
#define N_EDGES 640000
#define NPAD    20096   // 157 * 128

typedef __bf16 bf16_8 __attribute__((ext_vector_type(8)));
typedef float  f32_4  __attribute__((ext_vector_type(4)));
typedef unsigned short u16x4 __attribute__((ext_vector_type(4)));

// ---------------------------------------------------------------------------
// CSR build: count -> scan -> fill  (graph shared by all 3 layers)
// ---------------------------------------------------------------------------

__global__ void count_deg_kernel(const int* __restrict__ dst, int* __restrict__ deg) {
    int e = blockIdx.x * blockDim.x + threadIdx.x;
    if (e < N_EDGES) atomicAdd(&deg[dst[e]], 1);
}

__global__ __launch_bounds__(1024) void scan_deg_kernel(const int* __restrict__ deg,
                                                        int* __restrict__ row_start,
                                                        int* __restrict__ cursor,
                                                        float* __restrict__ dinv) {
    __shared__ int wsum[16];
    __shared__ int chunk_base;
    const int t = threadIdx.x, lane = t & 63, w = t >> 6;
    if (t == 0) chunk_base = 0;
    __syncthreads();
    for (int base = 0; base < N_NODES; base += 1024) {
        int i = base + t;
        int v = (i < N_NODES) ? deg[i] : 0;
        if (i < N_NODES) dinv[i] = rsqrtf((float)(v + 1));
        int incl = v;
        #pragma unroll
        for (int off = 1; off < 64; off <<= 1) {
            int u = __shfl_up(incl, off);
            if (lane >= off) incl += u;
        }
        if (lane == 63) wsum[w] = incl;
        __syncthreads();
        if (w == 0) {
            int s = (lane < 16) ? wsum[lane] : 0;
            #pragma unroll
            for (int off = 1; off < 16; off <<= 1) {
                int u = __shfl_up(s, off);
                if (lane >= off) s += u;
            }
            if (lane < 16) wsum[lane] = s;
        }
        __syncthreads();
        int wbase = (w == 0) ? 0 : wsum[w - 1];
        int excl  = chunk_base + wbase + incl - v;
        if (i < N_NODES) { row_start[i] = excl; cursor[i] = excl; }
        int total = wsum[15];
        __syncthreads();
        if (t == 0) chunk_base += total;
        __syncthreads();
    }
    if (t == 0) row_start[N_NODES] = chunk_base;
}

__global__ void fill_col_kernel(const int* __restrict__ src, const int* __restrict__ dst,
                                int* __restrict__ cursor, int* __restrict__ col) {
    int e = blockIdx.x * blockDim.x + threadIdx.x;
    if (e < N_EDGES) {
        int d = dst[e];
        int pos = atomicAdd(&cursor[d], 1);
        col[pos] = src[e];
    }
}

// xs0 = dinv (.) emb   [N,128] f32
__global__ __launch_bounds__(256) void scale_emb_kernel(const float* __restrict__ emb,
                                                        const float* __restrict__ dinv,
                                                        float* __restrict__ xs) {
    int tid = blockIdx.x * 256 + threadIdx.x;       // one float4 per thread
    if (tid >= N_NODES * 32) return;
    int n = tid >> 5;
    int q = (tid & 31) * 4;
    f32_4 v = *reinterpret_cast<const f32_4*>(emb + (size_t)n * 128 + q);
    float d = dinv[n];
    v.x *= d; v.y *= d; v.z *= d; v.w *= d;
    *reinterpret_cast<f32_4*>(xs + (size_t)n * 128 + q) = v;
}

// ---------------------------------------------------------------------------
// Aggregation (input pre-scaled by dinv): out[n] = dinv[n]*(sum xs[s] + xs[n])
// ONE WAVE PER NODE. Lane owns 4 channels (f32_4). Each edge's row is fetched
// by fully-coalesced dwordx4 instructions: M=256 -> 1 edge/instr (1024 B),
// M=128 -> 2 edges/instr (2 x 512 B). Edge indices broadcast via __shfl
// (no LDS, no barriers). 4 rows in flight.
// SPLIT: write bf16 hi/lo pair [n][2M] for the MFMA GEMM A-input.
// ---------------------------------------------------------------------------

__device__ inline ushort2 bf_split(float v) {
    __hip_bfloat16 h = __float2bfloat16(v);
    float hf = __bfloat162float(h);
    unsigned short lo = __hip_bfloat16_raw(__float2bfloat16(v - hf)).x;
    ushort2 r; r.x = __hip_bfloat16_raw(h).x; r.y = lo; return r;
}

template<int M, bool SPLIT, bool BIAS>
__global__ __launch_bounds__(256) void agg_kernel(const float* __restrict__ xs,
                                                  const int* __restrict__ rs,
                                                  const int* __restrict__ col,
                                                  const float* __restrict__ dinv,
                                                  const float* __restrict__ bias,
                                                  float* __restrict__ outf,
                                                  unsigned short* __restrict__ outb) {
    const int lane = threadIdx.x & 63;
    const int wid  = threadIdx.x >> 6;
    const int n    = blockIdx.x * 4 + wid;          // grid.x = 5000 -> n < 20000
    const float dn = dinv[n];
    const int s0 = rs[n], s1 = rs[n + 1];

    const int co   = (M == 256) ? (lane * 4) : ((lane & 31) * 4);  // channel offset
    const int half = (M == 256) ? 0 : (lane >> 5);                 // edge parity (M=128)

    f32_4 a0 = {0.f, 0.f, 0.f, 0.f}, a1 = a0, a2 = a0, a3 = a0;
    if (M == 256 || half == 0)
        a0 = *reinterpret_cast<const f32_4*>(xs + (size_t)n * M + co);   // self term

    for (int base = s0; base < s1; base += 64) {
        const int cnt = min(64, s1 - base);
        int myc = 0;
        if (lane < cnt) myc = __builtin_nontemporal_load(col + base + lane);  // coalesced
        int k = 0;
        if (M == 256) {
            for (; k + 3 < cnt; k += 4) {
                int sa = __shfl(myc, k),     sb = __shfl(myc, k + 1);
                int sc = __shfl(myc, k + 2), sd = __shfl(myc, k + 3);
                a0 += *reinterpret_cast<const f32_4*>(xs + (size_t)sa * M + co);
                a1 += *reinterpret_cast<const f32_4*>(xs + (size_t)sb * M + co);
                a2 += *reinterpret_cast<const f32_4*>(xs + (size_t)sc * M + co);
                a3 += *reinterpret_cast<const f32_4*>(xs + (size_t)sd * M + co);
            }
            for (; k < cnt; ++k) {
                int sa = __shfl(myc, k);
                a0 += *reinterpret_cast<const f32_4*>(xs + (size_t)sa * M + co);
            }
        } else {
            for (; k + 7 < cnt; k += 8) {
                int sa = __shfl(myc, k + half),     sb = __shfl(myc, k + 2 + half);
                int sc = __shfl(myc, k + 4 + half), sd = __shfl(myc, k + 6 + half);
                a0 += *reinterpret_cast<const f32_4*>(xs + (size_t)sa * M + co);
                a1 += *reinterpret_cast<const f32_4*>(xs + (size_t)sb * M + co);
                a2 += *reinterpret_cast<const f32_4*>(xs + (size_t)sc * M + co);
                a3 += *reinterpret_cast<const f32_4*>(xs + (size_t)sd * M + co);
            }
            for (; k < cnt; k += 2) {
                int idx = k + half;
                int sa = __shfl(myc, idx < cnt ? idx : 0);   // all lanes active at shfl
                f32_4 v = *reinterpret_cast<const f32_4*>(xs + (size_t)sa * M + co);
                if (idx < cnt) a0 += v;
            }
        }
    }

    f32_4 r = (a0 + a1) + (a2 + a3);
    if (M == 128) {
        r.x += __shfl_xor(r.x, 32);
        r.y += __shfl_xor(r.y, 32);
        r.z += __shfl_xor(r.z, 32);
        r.w += __shfl_xor(r.w, 32);
    }
    if (M == 256 || lane < 32) {
        r.x *= dn; r.y *= dn; r.z *= dn; r.w *= dn;
        if (BIAS) {
            r.x += bias[co + 0]; r.y += bias[co + 1];
            r.z += bias[co + 2]; r.w += bias[co + 3];
        }
        if (SPLIT) {
            ushort2 sx = bf_split(r.x), sy = bf_split(r.y), sz = bf_split(r.z), sw = bf_split(r.w);
            u16x4 hi = {sx.x, sy.x, sz.x, sw.x};
            u16x4 lo = {sx.y, sy.y, sz.y, sw.y};
            unsigned short* pb = outb + (size_t)n * (2 * M) + co;
            __builtin_nontemporal_store(hi, reinterpret_cast<u16x4*>(pb));
            __builtin_nontemporal_store(lo, reinterpret_cast<u16x4*>(pb + M));
        } else {
            __builtin_nontemporal_store(r, reinterpret_cast<f32_4*>(outf + (size_t)n * M + co));
        }
    }
}

// ---------------------------------------------------------------------------
// fp32 X[N][256] -> bf16 hi/lo [NPAD][512], pad rows zero-filled
// ---------------------------------------------------------------------------

__global__ __launch_bounds__(256) void convA256_kernel(const float* __restrict__ X,
                                                       unsigned short* __restrict__ Ae) {
    const int tid = blockIdx.x * blockDim.x + threadIdx.x;
    if (tid >= NPAD * 64) return;
    const int n = tid >> 6;
    const int q = (tid & 63) * 4;
    f32_4 v = {0.f, 0.f, 0.f, 0.f};
    if (n < N_NODES) v = *reinterpret_cast<const f32_4*>(X + (size_t)n * 256 + q);
    ushort2 sx = bf_split(v.x), sy = bf_split(v.y), sz = bf_split(v.z), sw = bf_split(v.w);
    u16x4 hi = {sx.x, sy.x, sz.x, sw.x};
    u16x4 lo = {sx.y, sy.y, sz.y, sw.y};
    *reinterpret_cast<u16x4*>(Ae + (size_t)n * 512 + q)       = hi;
    *reinterpret_cast<u16x4*>(Ae + (size_t)n * 512 + 256 + q) = lo;
}

// W[K][M] fp32 -> BT [M][2K] bf16
template<int K, int M>
__global__ __launch_bounds__(256) void convW_kernel(const float* __restrict__ W,
                                                    unsigned short* __restrict__ BT) {
    const int tid = blockIdx.x * blockDim.x + threadIdx.x;
    if (tid >= K * M) return;
    const int k = tid / M;
    const int m = tid - k * M;
    ushort2 s = bf_split(W[(size_t)k * M + m]);
    BT[(size_t)m * (2 * K) + k]     = s.x;
    BT[(size_t)m * (2 * K) + K + k] = s.y;
}

// ---------------------------------------------------------------------------
// MFMA GEMM, 3-segment bf16 hi/lo split: C = Ahi*Bhi + Ahi*Blo + Alo*Bhi
// Tile 128 x BN (BN=64|128), 4 waves (2x2), BK=32, 16x16x32 bf16.
// Epilogue: optional relu(v+bias), optional *dinv[row] (pre-scale for next agg).
// ---------------------------------------------------------------------------

template<int K, int BN, bool RELU, bool SCALE>
__global__ __launch_bounds__(256) void mfma_gemm_kernel(const unsigned short* __restrict__ Ae, // [NPAD][2K]
                                                        const unsigned short* __restrict__ BT, // [M][2K]
                                                        const float* __restrict__ bias,
                                                        const float* __restrict__ dinv,
                                                        float* __restrict__ C, int Mout) {
    constexpr int K2 = 2 * K;
    constexpr int CF = BN / 32;          // b-fragments per wave (2 or 4)
    __shared__ unsigned short As[128 * 32];
    __shared__ unsigned short Bs[BN * 32];
    const int tid  = threadIdx.x;
    const int lane = tid & 63;
    const int wid  = tid >> 6;
    const int brow = blockIdx.x * 128;
    const int bcol = blockIdx.y * BN;
    const int wr = wid & 1, wc = wid >> 1;

    const int arow0 = wid * 32 + (lane >> 2);        // staged A row
    const int bcol0 = wid * (BN / 4) + (lane >> 2);  // staged B col
    const int ke8   = (lane & 3) * 8;

    f32_4 acc[4][CF];
    #pragma unroll
    for (int r = 0; r < 4; ++r)
        #pragma unroll
        for (int c = 0; c < CF; ++c) acc[r][c] = (f32_4){0.f, 0.f, 0.f, 0.f};

    for (int ks = 0; ks < 3 * K / 32; ++ks) {
        const int k0  = ks * 32;
        const int seg = k0 / K;
        const int kk  = k0 - seg * K;
        const int aoff = (seg == 2) ? K + kk : kk;   // A: hi, hi, lo
        const int boff = (seg == 1) ? K + kk : kk;   // B: hi, lo, hi

        const unsigned short* g0 = Ae + (size_t)(brow + arow0) * K2 + aoff + ke8;
        const unsigned short* g1 = g0 + (size_t)16 * K2;
        char* l0 = (char*)As + wid * 2048;
        __builtin_amdgcn_global_load_lds((const __attribute__((address_space(1))) void*)g0,
                                         (__attribute__((address_space(3))) void*)l0, 16, 0, 0);
        __builtin_amdgcn_global_load_lds((const __attribute__((address_space(1))) void*)g1,
                                         (__attribute__((address_space(3))) void*)(l0 + 1024), 16, 0, 0);
        const unsigned short* gb = BT + (size_t)(bcol + bcol0) * K2 + boff + ke8;
        char* lb = (char*)Bs + wid * (BN * 16);      // 16 (BN=64) or 32 (BN=128) cols/wave, 64 B/col
        __builtin_amdgcn_global_load_lds((const __attribute__((address_space(1))) void*)gb,
                                         (__attribute__((address_space(3))) void*)lb, 16, 0, 0);
        if constexpr (BN == 128) {
            const unsigned short* gb2 = gb + (size_t)16 * K2;
            __builtin_amdgcn_global_load_lds((const __attribute__((address_space(1))) void*)gb2,
                                             (__attribute__((address_space(3))) void*)(lb + 1024), 16, 0, 0);
        }
        __syncthreads();

        bf16_8 a[4], b[CF];
        #pragma unroll
        for (int r = 0; r < 4; ++r) {
            int off = (wr * 64 + r * 16 + (lane & 15)) * 32 + (lane >> 4) * 8;
            a[r] = *reinterpret_cast<const bf16_8*>(&As[off]);
        }
        #pragma unroll
        for (int c = 0; c < CF; ++c) {
            int off = (wc * (BN / 2) + c * 16 + (lane & 15)) * 32 + (lane >> 4) * 8;
            b[c] = *reinterpret_cast<const bf16_8*>(&Bs[off]);
        }
        #pragma unroll
        for (int r = 0; r < 4; ++r)
            #pragma unroll
            for (int c = 0; c < CF; ++c)
                acc[r][c] = __builtin_amdgcn_mfma_f32_16x16x32_bf16(a[r], b[c], acc[r][c], 0, 0, 0);
        __syncthreads();
    }

    // Epilogue: C/D layout col=lane&15, row=(lane>>4)*4+q
    #pragma unroll
    for (int r = 0; r < 4; ++r) {
        const int row0 = brow + wr * 64 + r * 16 + (lane >> 4) * 4;
        f32_4 dv = {1.f, 1.f, 1.f, 1.f};
        if (SCALE) dv = *reinterpret_cast<const f32_4*>(dinv + row0);   // quad-aligned
        #pragma unroll
        for (int c = 0; c < CF; ++c) {
            const int n  = bcol + wc * (BN / 2) + c * 16 + (lane & 15);
            const float bv = RELU ? bias[n] : 0.f;
            #pragma unroll
            for (int q = 0; q < 4; ++q) {
                const int row = row0 + q;
                if (row < N_NODES) {
                    float v = acc[r][c][q];
                    if (RELU)  v = fmaxf(v + bv, 0.f);
                    if (SCALE) v *= dv[q];
                    C[(size_t)row * Mout + n] = v;
                }
            }
        }
    }
}

// ---------------------------------------------------------------------------
// Launch
// ---------------------------------------------------------------------------

static inline char* align_up(char* p, size_t a) {
    return (char*)(((uintptr_t)p + a - 1) & ~(a - 1));
}

extern "C" void kernel_launch(void* const* d_in, const int* in_sizes, int n_in,
                              void* d_out, int out_size, void* d_ws, size_t ws_size,
                              hipStream_t stream) {
    const int*   edge_index = (const int*)d_in[0];
    const float* node_emb   = (const float*)d_in[1];
    const float* W1 = (const float*)d_in[2];
    const float* b1 = (const float*)d_in[3];
    const float* W2 = (const float*)d_in[4];
    const float* b2 = (const float*)d_in[5];
    const float* W3 = (const float*)d_in[6];
    const float* b3 = (const float*)d_in[7];
    float* out = (float*)d_out;

    const int* src = edge_index;
    const int* dst = edge_index + N_EDGES;

    // Workspace carve-up (~45 MB)
    char* p = (char*)d_ws;
    int* deg       = (int*)p;            p = align_up(p + N_NODES * sizeof(int), 256);
    int* rs        = (int*)p;            p = align_up(p + (N_NODES + 1) * sizeof(int), 256);
    int* cursor    = (int*)p;            p = align_up(p + N_NODES * sizeof(int), 256);
    int* col       = (int*)p;            p = align_up(p + N_EDGES * sizeof(int), 256);
    float* dinv    = (float*)p;          p = align_up(p + N_NODES * sizeof(float), 512);
    unsigned short* BT = (unsigned short*)p; p = align_up(p + 256 * 512 * sizeof(unsigned short), 256);
    const size_t SLOT = (size_t)NPAD * 512 * 2;   // 20.58 MB, fits [N,256]f32 or [NPAD][512]bf16
    char* slotA = p;                     p = align_up(p + SLOT, 256);
    char* slotB = p;                     p = align_up(p + SLOT, 256);

    float*          fA = (float*)slotA;
    unsigned short* uB = (unsigned short*)slotB;

    // --- CSR + dinv ---
    hipMemsetAsync(deg, 0, N_NODES * sizeof(int), stream);
    count_deg_kernel<<<(N_EDGES + 255) / 256, 256, 0, stream>>>(dst, deg);
    scan_deg_kernel<<<1, 1024, 0, stream>>>(deg, rs, cursor, dinv);
    fill_col_kernel<<<(N_EDGES + 255) / 256, 256, 0, stream>>>(src, dst, cursor, col);

    // xs0 = dinv (.) emb  -> slotA
    scale_emb_kernel<<<(N_NODES * 32 + 255) / 256, 256, 0, stream>>>(node_emb, dinv, fA);

    // --- Layer 1: agg1 -> Ae1(bf16, slotB); G1 = relu(.@W1+b1)*dinv -> X(f32, slotA)
    agg_kernel<128, true, false><<<5000, 256, 0, stream>>>(fA, rs, col, dinv, nullptr, nullptr, uB);
    convW_kernel<128, 256><<<(128 * 256) / 256, 256, 0, stream>>>(W1, BT);
    mfma_gemm_kernel<128, 128, true, true><<<dim3(NPAD / 128, 2), 256, 0, stream>>>(uB, BT, b1, dinv, fA, 256);

    // --- Layer 2: agg2 -> Ae2(bf16, slotB); G2 = relu(.@W2+b2) -> H(f32, slotA)
    agg_kernel<256, true, false><<<5000, 256, 0, stream>>>(fA, rs, col, dinv, nullptr, nullptr, uB);
    convW_kernel<256, 256><<<(256 * 256) / 256, 256, 0, stream>>>(W2, BT);
    mfma_gemm_kernel<256, 128, true, false><<<dim3(NPAD / 128, 2), 256, 0, stream>>>(uB, BT, b2, dinv, fA, 256);

    // --- Layer 3: conv H -> He(bf16, slotB); G3 = (.@W3)*dinv -> G(f32, slotA); agg3 -> out
    convA256_kernel<<<(NPAD * 64 + 255) / 256, 256, 0, stream>>>(fA, uB);
    convW_kernel<256, 128><<<(256 * 128) / 256, 256, 0, stream>>>(W3, BT);
    mfma_gemm_kernel<256, 64, false, true><<<dim3(NPAD / 128, 2), 256, 0, stream>>>(uB, BT, nullptr, dinv, fA, 128);
    agg_kernel<128, false, true><<<5000, 256, 0, stream>>>(fA, rs, col, dinv, b3, out, nullptr);
}

// Round 12
// 303.883 us; speedup vs baseline: 1.5308x; 1.3383x over previous
//
#include <hip/hip_runtime.h>
#include <hip/hip_bf16.h>
#include <cstdint>

#define N_NODES 20000
#define N_EDGES 640000
#define NPAD    20096   // 157 * 128

typedef __bf16 bf16_8 __attribute__((ext_vector_type(8)));
typedef float  f32_4  __attribute__((ext_vector_type(4)));
typedef unsigned short u16x4 __attribute__((ext_vector_type(4)));

__device__ inline unsigned short bf_hi(float v) {
    return __hip_bfloat16_raw(__float2bfloat16(v)).x;       // RNE
}
__device__ inline ushort2 bf_split(float v) {
    __hip_bfloat16 h = __float2bfloat16(v);
    float hf = __bfloat162float(h);
    ushort2 r; r.x = __hip_bfloat16_raw(h).x;
    r.y = __hip_bfloat16_raw(__float2bfloat16(v - hf)).x;
    return r;
}
__device__ inline f32_4 b2f4(u16x4 v) {
    f32_4 r;
    r.x = __uint_as_float(((unsigned)v.x) << 16);
    r.y = __uint_as_float(((unsigned)v.y) << 16);
    r.z = __uint_as_float(((unsigned)v.z) << 16);
    r.w = __uint_as_float(((unsigned)v.w) << 16);
    return r;
}

// ---------------------------------------------------------------------------
// CSR build: count -> parallel scan (3 small kernels) -> fill
// ---------------------------------------------------------------------------

__global__ void count_deg_kernel(const int* __restrict__ dst, int* __restrict__ deg) {
    int e = blockIdx.x * blockDim.x + threadIdx.x;
    if (e < N_EDGES) atomicAdd(&deg[dst[e]], 1);
}

__global__ __launch_bounds__(256) void scanA_kernel(const int* __restrict__ deg,
                                                    float* __restrict__ dinv,
                                                    int* __restrict__ bsum) {
    const int b = blockIdx.x, t = threadIdx.x, i = b * 256 + t;
    int v = (i < N_NODES) ? deg[i] : 0;
    if (i < N_NODES) dinv[i] = rsqrtf((float)(v + 1));
    int s = v;
    #pragma unroll
    for (int off = 1; off < 64; off <<= 1) s += __shfl_xor(s, off);
    __shared__ int ws[4];
    if ((t & 63) == 0) ws[t >> 6] = s;
    __syncthreads();
    if (t == 0) bsum[b] = ws[0] + ws[1] + ws[2] + ws[3];
}

__global__ __launch_bounds__(128) void scanB_kernel(const int* __restrict__ bsum,
                                                    int* __restrict__ boff,
                                                    int* __restrict__ row_start,
                                                    int nblk) {
    __shared__ int s[128];
    const int t = threadIdx.x;
    int v = (t < nblk) ? bsum[t] : 0;
    s[t] = v;
    __syncthreads();
    for (int off = 1; off < 128; off <<= 1) {
        int u = (t >= off) ? s[t - off] : 0;
        __syncthreads();
        s[t] += u;
        __syncthreads();
    }
    if (t < nblk) boff[t] = s[t] - v;
    if (t == 127) row_start[N_NODES] = s[127];
}

__global__ __launch_bounds__(256) void scanC_kernel(const int* __restrict__ deg,
                                                    const int* __restrict__ boff,
                                                    int* __restrict__ row_start,
                                                    int* __restrict__ cursor) {
    const int b = blockIdx.x, t = threadIdx.x, i = b * 256 + t;
    const int lane = t & 63, w = t >> 6;
    int v = (i < N_NODES) ? deg[i] : 0;
    int incl = v;
    #pragma unroll
    for (int off = 1; off < 64; off <<= 1) {
        int u = __shfl_up(incl, off);
        if (lane >= off) incl += u;
    }
    __shared__ int ws[4];
    if (lane == 63) ws[w] = incl;
    __syncthreads();
    int woff = 0;
    for (int j = 0; j < w; ++j) woff += ws[j];
    int excl = boff[b] + woff + incl - v;
    if (i < N_NODES) { row_start[i] = excl; cursor[i] = excl; }
}

__global__ void fill_col_kernel(const int* __restrict__ src, const int* __restrict__ dst,
                                int* __restrict__ cursor, int* __restrict__ col) {
    int e = blockIdx.x * blockDim.x + threadIdx.x;
    if (e < N_EDGES) {
        int d = dst[e];
        int pos = atomicAdd(&cursor[d], 1);
        col[pos] = src[e];
    }
}

// xsb = bf16(dinv (.) emb)   [N,128]
__global__ __launch_bounds__(256) void scale_emb_kernel(const float* __restrict__ emb,
                                                        const float* __restrict__ dinv,
                                                        unsigned short* __restrict__ xsb) {
    int tid = blockIdx.x * 256 + threadIdx.x;
    if (tid >= N_NODES * 32) return;
    int n = tid >> 5;
    int q = (tid & 31) * 4;
    f32_4 v = *reinterpret_cast<const f32_4*>(emb + (size_t)n * 128 + q);
    float d = dinv[n];
    u16x4 o = {bf_hi(v.x * d), bf_hi(v.y * d), bf_hi(v.z * d), bf_hi(v.w * d)};
    *reinterpret_cast<u16x4*>(xsb + (size_t)n * 128 + q) = o;
}

// ---------------------------------------------------------------------------
// bf16 aggregation: out[n] = dinv[n]*(sum xs[s] + xs[n])  (inputs pre-scaled)
// One wave per node; lane owns 4 channels (u16x4, 8B). M=256: 1 edge/instr
// (512B contiguous). M=128: 2 edges/instr. f32 accumulate.
// SPLIT: emit bf16 hi/lo [n][2M] (GEMM A). Else: f32 out (+bias) — final layer.
// ---------------------------------------------------------------------------

template<int M, bool SPLIT, bool BIAS>
__global__ __launch_bounds__(256) void agg_kernel(const unsigned short* __restrict__ xs,
                                                  const int* __restrict__ rs,
                                                  const int* __restrict__ col,
                                                  const float* __restrict__ dinv,
                                                  const float* __restrict__ bias,
                                                  float* __restrict__ outf,
                                                  unsigned short* __restrict__ outb) {
    const int lane = threadIdx.x & 63;
    const int wid  = threadIdx.x >> 6;
    const int n    = blockIdx.x * 4 + wid;          // grid.x = 5000
    const float dn = dinv[n];
    const int s0 = rs[n], s1 = rs[n + 1];

    const int co   = (M == 256) ? (lane * 4) : ((lane & 31) * 4);
    const int half = (M == 256) ? 0 : (lane >> 5);

    f32_4 a0 = {0.f, 0.f, 0.f, 0.f}, a1 = a0, a2 = a0, a3 = a0;
    if (M == 256 || half == 0)
        a0 = b2f4(*reinterpret_cast<const u16x4*>(xs + (size_t)n * M + co));   // self

    for (int base = s0; base < s1; base += 64) {
        const int cnt = min(64, s1 - base);
        int myc = 0;
        if (lane < cnt) myc = __builtin_nontemporal_load(col + base + lane);
        int k = 0;
        if (M == 256) {
            for (; k + 3 < cnt; k += 4) {
                int sa = __shfl(myc, k),     sb = __shfl(myc, k + 1);
                int sc = __shfl(myc, k + 2), sd = __shfl(myc, k + 3);
                a0 += b2f4(*reinterpret_cast<const u16x4*>(xs + (size_t)sa * M + co));
                a1 += b2f4(*reinterpret_cast<const u16x4*>(xs + (size_t)sb * M + co));
                a2 += b2f4(*reinterpret_cast<const u16x4*>(xs + (size_t)sc * M + co));
                a3 += b2f4(*reinterpret_cast<const u16x4*>(xs + (size_t)sd * M + co));
            }
            for (; k < cnt; ++k) {
                int sa = __shfl(myc, k);
                a0 += b2f4(*reinterpret_cast<const u16x4*>(xs + (size_t)sa * M + co));
            }
        } else {
            for (; k + 7 < cnt; k += 8) {
                int sa = __shfl(myc, k + half),     sb = __shfl(myc, k + 2 + half);
                int sc = __shfl(myc, k + 4 + half), sd = __shfl(myc, k + 6 + half);
                a0 += b2f4(*reinterpret_cast<const u16x4*>(xs + (size_t)sa * M + co));
                a1 += b2f4(*reinterpret_cast<const u16x4*>(xs + (size_t)sb * M + co));
                a2 += b2f4(*reinterpret_cast<const u16x4*>(xs + (size_t)sc * M + co));
                a3 += b2f4(*reinterpret_cast<const u16x4*>(xs + (size_t)sd * M + co));
            }
            for (; k < cnt; k += 2) {
                int idx = k + half;
                int sa = __shfl(myc, idx < cnt ? idx : 0);
                f32_4 v = b2f4(*reinterpret_cast<const u16x4*>(xs + (size_t)sa * M + co));
                if (idx < cnt) a0 += v;
            }
        }
    }

    f32_4 r = (a0 + a1) + (a2 + a3);
    if (M == 128) {
        r.x += __shfl_xor(r.x, 32);
        r.y += __shfl_xor(r.y, 32);
        r.z += __shfl_xor(r.z, 32);
        r.w += __shfl_xor(r.w, 32);
    }
    if (M == 256 || lane < 32) {
        r.x *= dn; r.y *= dn; r.z *= dn; r.w *= dn;
        if (BIAS) {
            r.x += bias[co + 0]; r.y += bias[co + 1];
            r.z += bias[co + 2]; r.w += bias[co + 3];
        }
        if (SPLIT) {
            ushort2 sx = bf_split(r.x), sy = bf_split(r.y), sz = bf_split(r.z), sw = bf_split(r.w);
            u16x4 hi = {sx.x, sy.x, sz.x, sw.x};
            u16x4 lo = {sx.y, sy.y, sz.y, sw.y};
            unsigned short* pb = outb + (size_t)n * (2 * M) + co;
            __builtin_nontemporal_store(hi, reinterpret_cast<u16x4*>(pb));
            __builtin_nontemporal_store(lo, reinterpret_cast<u16x4*>(pb + M));
        } else {
            __builtin_nontemporal_store(r, reinterpret_cast<f32_4*>(outf + (size_t)n * M + co));
        }
    }
}

// W[K][M] fp32 -> BT [M][2K] bf16
template<int K, int M>
__global__ __launch_bounds__(256) void convW_kernel(const float* __restrict__ W,
                                                    unsigned short* __restrict__ BT) {
    const int tid = blockIdx.x * blockDim.x + threadIdx.x;
    if (tid >= K * M) return;
    const int k = tid / M;
    const int m = tid - k * M;
    ushort2 s = bf_split(W[(size_t)k * M + m]);
    BT[(size_t)m * (2 * K) + k]     = s.x;
    BT[(size_t)m * (2 * K) + K + k] = s.y;
}

// ---------------------------------------------------------------------------
// MFMA GEMM, 3-segment bf16 hi/lo split: C = Ahi*Bhi + Ahi*Blo + Alo*Bhi
// Tile 128 x BN, 4 waves, BK=32, 16x16x32 bf16.
// Epilogue -> bf16: SPLITOUT ? hi/lo [row][2*Mout] : single bf16 [row][Mout].
// ---------------------------------------------------------------------------

template<int K, int BN, bool RELU, bool SCALE, bool SPLITOUT>
__global__ __launch_bounds__(256) void mfma_gemm_kernel(const unsigned short* __restrict__ Ae, // [NPAD][2K]
                                                        const unsigned short* __restrict__ BT, // [M][2K]
                                                        const float* __restrict__ bias,
                                                        const float* __restrict__ dinv,
                                                        unsigned short* __restrict__ C, int Mout) {
    constexpr int K2 = 2 * K;
    constexpr int CF = BN / 32;
    __shared__ unsigned short As[128 * 32];
    __shared__ unsigned short Bs[BN * 32];
    const int tid  = threadIdx.x;
    const int lane = tid & 63;
    const int wid  = tid >> 6;
    const int brow = blockIdx.x * 128;
    const int bcol = blockIdx.y * BN;
    const int wr = wid & 1, wc = wid >> 1;

    const int arow0 = wid * 32 + (lane >> 2);
    const int bcol0 = wid * (BN / 4) + (lane >> 2);
    const int ke8   = (lane & 3) * 8;

    f32_4 acc[4][CF];
    #pragma unroll
    for (int r = 0; r < 4; ++r)
        #pragma unroll
        for (int c = 0; c < CF; ++c) acc[r][c] = (f32_4){0.f, 0.f, 0.f, 0.f};

    for (int ks = 0; ks < 3 * K / 32; ++ks) {
        const int k0  = ks * 32;
        const int seg = k0 / K;
        const int kk  = k0 - seg * K;
        const int aoff = (seg == 2) ? K + kk : kk;   // A: hi, hi, lo
        const int boff = (seg == 1) ? K + kk : kk;   // B: hi, lo, hi

        const unsigned short* g0 = Ae + (size_t)(brow + arow0) * K2 + aoff + ke8;
        const unsigned short* g1 = g0 + (size_t)16 * K2;
        char* l0 = (char*)As + wid * 2048;
        __builtin_amdgcn_global_load_lds((const __attribute__((address_space(1))) void*)g0,
                                         (__attribute__((address_space(3))) void*)l0, 16, 0, 0);
        __builtin_amdgcn_global_load_lds((const __attribute__((address_space(1))) void*)g1,
                                         (__attribute__((address_space(3))) void*)(l0 + 1024), 16, 0, 0);
        const unsigned short* gb = BT + (size_t)(bcol + bcol0) * K2 + boff + ke8;
        char* lb = (char*)Bs + wid * (BN * 16);
        __builtin_amdgcn_global_load_lds((const __attribute__((address_space(1))) void*)gb,
                                         (__attribute__((address_space(3))) void*)lb, 16, 0, 0);
        if constexpr (BN == 128) {
            const unsigned short* gb2 = gb + (size_t)16 * K2;
            __builtin_amdgcn_global_load_lds((const __attribute__((address_space(1))) void*)gb2,
                                             (__attribute__((address_space(3))) void*)(lb + 1024), 16, 0, 0);
        }
        __syncthreads();

        bf16_8 a[4], b[CF];
        #pragma unroll
        for (int r = 0; r < 4; ++r) {
            int off = (wr * 64 + r * 16 + (lane & 15)) * 32 + (lane >> 4) * 8;
            a[r] = *reinterpret_cast<const bf16_8*>(&As[off]);
        }
        #pragma unroll
        for (int c = 0; c < CF; ++c) {
            int off = (wc * (BN / 2) + c * 16 + (lane & 15)) * 32 + (lane >> 4) * 8;
            b[c] = *reinterpret_cast<const bf16_8*>(&Bs[off]);
        }
        #pragma unroll
        for (int r = 0; r < 4; ++r)
            #pragma unroll
            for (int c = 0; c < CF; ++c)
                acc[r][c] = __builtin_amdgcn_mfma_f32_16x16x32_bf16(a[r], b[c], acc[r][c], 0, 0, 0);
        __syncthreads();
    }

    // Epilogue: C/D layout col=lane&15, row=(lane>>4)*4+q
    #pragma unroll
    for (int r = 0; r < 4; ++r) {
        const int row0 = brow + wr * 64 + r * 16 + (lane >> 4) * 4;
        f32_4 dv = {1.f, 1.f, 1.f, 1.f};
        if (SCALE) dv = *reinterpret_cast<const f32_4*>(dinv + row0);
        #pragma unroll
        for (int c = 0; c < CF; ++c) {
            const int n  = bcol + wc * (BN / 2) + c * 16 + (lane & 15);
            const float bv = RELU ? bias[n] : 0.f;
            #pragma unroll
            for (int q = 0; q < 4; ++q) {
                const int row = row0 + q;
                if (row < N_NODES) {
                    float v = acc[r][c][q];
                    if (RELU)  v = fmaxf(v + bv, 0.f);
                    if (SCALE) v *= dv[q];
                    if (SPLITOUT) {
                        ushort2 s = bf_split(v);
                        C[(size_t)row * (2 * Mout) + n]        = s.x;
                        C[(size_t)row * (2 * Mout) + Mout + n] = s.y;
                    } else {
                        C[(size_t)row * Mout + n] = bf_hi(v);
                    }
                }
            }
        }
    }
}

// ---------------------------------------------------------------------------
// Launch
// ---------------------------------------------------------------------------

static inline char* align_up(char* p, size_t a) {
    return (char*)(((uintptr_t)p + a - 1) & ~(a - 1));
}

extern "C" void kernel_launch(void* const* d_in, const int* in_sizes, int n_in,
                              void* d_out, int out_size, void* d_ws, size_t ws_size,
                              hipStream_t stream) {
    const int*   edge_index = (const int*)d_in[0];
    const float* node_emb   = (const float*)d_in[1];
    const float* W1 = (const float*)d_in[2];
    const float* b1 = (const float*)d_in[3];
    const float* W2 = (const float*)d_in[4];
    const float* b2 = (const float*)d_in[5];
    const float* W3 = (const float*)d_in[6];
    const float* b3 = (const float*)d_in[7];
    float* out = (float*)d_out;

    const int* src = edge_index;
    const int* dst = edge_index + N_EDGES;

    const int NB = (N_NODES + 255) / 256;   // 79 scan blocks

    // Workspace carve-up (~44.6 MB)
    char* p = (char*)d_ws;
    int* deg       = (int*)p;            p = align_up(p + N_NODES * sizeof(int), 256);
    int* rs        = (int*)p;            p = align_up(p + (N_NODES + 1) * sizeof(int), 256);
    int* cursor    = (int*)p;            p = align_up(p + N_NODES * sizeof(int), 256);
    int* col       = (int*)p;            p = align_up(p + N_EDGES * sizeof(int), 256);
    float* dinv    = (float*)p;          p = align_up(p + N_NODES * sizeof(float), 512);
    int* bsum      = (int*)p;            p = align_up(p + NB * sizeof(int), 256);
    int* boff      = (int*)p;            p = align_up(p + NB * sizeof(int), 256);
    unsigned short* BT = (unsigned short*)p; p = align_up(p + 256 * 512 * sizeof(unsigned short), 256);
    const size_t SLOT = (size_t)NPAD * 512 * 2;   // 20.58 MB
    char* slotA = p;                     p = align_up(p + SLOT, 256);
    char* slotB = p;                     p = align_up(p + SLOT, 256);

    unsigned short* uA = (unsigned short*)slotA;
    unsigned short* uB = (unsigned short*)slotB;

    // --- CSR + dinv (parallel scan) ---
    hipMemsetAsync(deg, 0, N_NODES * sizeof(int), stream);
    count_deg_kernel<<<(N_EDGES + 255) / 256, 256, 0, stream>>>(dst, deg);
    scanA_kernel<<<NB, 256, 0, stream>>>(deg, dinv, bsum);
    scanB_kernel<<<1, 128, 0, stream>>>(bsum, boff, rs, NB);
    scanC_kernel<<<NB, 256, 0, stream>>>(deg, boff, rs, cursor);
    fill_col_kernel<<<(N_EDGES + 255) / 256, 256, 0, stream>>>(src, dst, cursor, col);

    // xsb = bf16(dinv (.) emb) -> slotA [N,128]
    scale_emb_kernel<<<(N_NODES * 32 + 255) / 256, 256, 0, stream>>>(node_emb, dinv, uA);

    // --- Layer 1: agg1(xsb) -> Ae1 hi/lo [N,256] (slotB); GEMM1 -> h1s bf16 [N,256] (slotA)
    agg_kernel<128, true, false><<<5000, 256, 0, stream>>>(uA, rs, col, dinv, nullptr, nullptr, uB);
    convW_kernel<128, 256><<<(128 * 256) / 256, 256, 0, stream>>>(W1, BT);
    mfma_gemm_kernel<128, 128, true, true, false><<<dim3(NPAD / 128, 2), 256, 0, stream>>>(uB, BT, b1, dinv, uA, 256);

    // --- Layer 2: agg2(h1s) -> Ae2 hi/lo [N,512] (slotB); GEMM2 -> h2e hi/lo [N,512] (slotA)
    agg_kernel<256, true, false><<<5000, 256, 0, stream>>>(uA, rs, col, dinv, nullptr, nullptr, uB);
    convW_kernel<256, 256><<<(256 * 256) / 256, 256, 0, stream>>>(W2, BT);
    mfma_gemm_kernel<256, 128, true, false, true><<<dim3(NPAD / 128, 2), 256, 0, stream>>>(uB, BT, b2, dinv, uA, 256);

    // --- Layer 3: GEMM3(h2e) -> g3s bf16 [N,128] (slotB); agg3 -> out f32 (+b3)
    convW_kernel<256, 128><<<(256 * 128) / 256, 256, 0, stream>>>(W3, BT);
    mfma_gemm_kernel<256, 64, false, true, false><<<dim3(NPAD / 128, 2), 256, 0, stream>>>(uA, BT, nullptr, dinv, uB, 128);
    agg_kernel<128, false, true><<<5000, 256, 0, stream>>>(uB, rs, col, dinv, b3, out, nullptr);
}